// Round 2
// baseline (214.480 us; speedup 1.0000x reference)
//
#include <hip/hip_runtime.h>
#include <hip/hip_bf16.h>
#include <stdint.h>

typedef __bf16 bf16x8 __attribute__((ext_vector_type(8)));
typedef float  f32x16 __attribute__((ext_vector_type(16)));

#define T_INV 5.0f
#define K2EXP 7.2134752044448170f   /* log2(e)/T */
#define LN2F  0.6931471805599453f

__device__ __forceinline__ unsigned short f2bf(float f) {
  __bf16 h = (__bf16)f;
  return __builtin_bit_cast(unsigned short, h);
}

// ghat: row-normalized g_enc as bf16, pre-swizzled: byte kb of row r lands at
// r*512 + (kb ^ ((r&31)<<4))  -- full 32-slot XOR permutation per 512B row.
__global__ __launch_bounds__(256) void k_ghat(const float* __restrict__ g,
                                              char* __restrict__ ghat) {
  const int w = threadIdx.x >> 6, l = threadIdx.x & 63;
  const int row = blockIdx.x * 4 + w;
  const float4 v = *(const float4*)(g + (size_t)row * 256 + l * 4);
  float s = v.x * v.x + v.y * v.y + v.z * v.z + v.w * v.w;
  #pragma unroll
  for (int m = 1; m <= 32; m <<= 1) s += __shfl_xor(s, m, 64);
  const float rn = rsqrtf(s);
  ushort4 o;
  o.x = f2bf(v.x * rn); o.y = f2bf(v.y * rn);
  o.z = f2bf(v.z * rn); o.w = f2bf(v.w * rn);
  const int off = row * 512 + ((l * 8) ^ ((row & 31) << 4));
  *(ushort4*)(ghat + off) = o;
}

// Fused main kernel: 8 waves/block, 64 rows/wave (A normalized in-register,
// k=256 resident), B double-buffered through LDS in 64KB chunks, fused
// exp/row-sum epilogue, single HBM pass over l_enc (norm folded in).
__global__ __launch_bounds__(512, 2) void k_main(const float* __restrict__ l2,
                                                 const char* __restrict__ ghat,
                                                 float* __restrict__ out) {
  __shared__ __align__(16) char smem[2 * 65536 + 2048 + 64];
  float* posl = (float*)(smem + 131072);          // 512 floats
  float* bsum = (float*)(smem + 131072 + 2048);

  const int tid = threadIdx.x;
  const int w   = tid >> 6;      // 0..7
  const int l   = tid & 63;
  const int lm  = l & 31;
  const int lh  = l >> 5;
  const int wrb = blockIdx.x * 512 + w * 64;  // wave's first row
  const int p   = wrb >> 7;                   // positive column (wave-uniform)
  const int pcf = p >> 5;                     // global 32-col fragment of p

  if (tid == 0) *bsum = 0.f;

  auto stage = [&](int c, int buf) {
    const char* gsrc = ghat + c * 65536 + w * 8192 + l * 16;
    char* ldst = smem + buf * 65536 + w * 8192;
    #pragma unroll
    for (int i = 0; i < 8; ++i) {
      __builtin_amdgcn_global_load_lds(
          (const __attribute__((address_space(1))) void*)(gsrc + i * 1024),
          (__attribute__((address_space(3))) void*)(ldst + i * 1024),
          16, 0, 0);
    }
  };

  stage(0, 0);  // fly under the A-load

  // A load + pack (unnormalized) + sum-of-squares, single HBM pass.
  // af[g2][s]: row wrb+g2*32+lm, k = s*16 + lh*8 .. +8
  bf16x8 af[2][16];
  float ss[2];
  #pragma unroll
  for (int g2 = 0; g2 < 2; ++g2) {
    const int row = wrb + g2 * 32 + lm;
    const float* rp = l2 + (size_t)row * 256 + lh * 8;
    float acc = 0.f;
    #pragma unroll
    for (int s = 0; s < 16; ++s) {
      const float4 a = *(const float4*)(rp + s * 16);
      const float4 b = *(const float4*)(rp + s * 16 + 4);
      acc += a.x*a.x + a.y*a.y + a.z*a.z + a.w*a.w
           + b.x*b.x + b.y*b.y + b.z*b.z + b.w*b.w;
      bf16x8 f;
      f[0] = (__bf16)a.x; f[1] = (__bf16)a.y; f[2] = (__bf16)a.z; f[3] = (__bf16)a.w;
      f[4] = (__bf16)b.x; f[5] = (__bf16)b.y; f[6] = (__bf16)b.z; f[7] = (__bf16)b.w;
      af[g2][s] = f;
    }
    ss[g2] = acc;
  }
  // fold 1/||row|| into af in-register (2 bf16 roundings total, ~2e-3 on loss)
  #pragma unroll
  for (int g2 = 0; g2 < 2; ++g2) {
    const float t = ss[g2] + __shfl_xor(ss[g2], 32, 64);
    const float rn = rsqrtf(t);
    #pragma unroll
    for (int s = 0; s < 16; ++s) {
      bf16x8 f = af[g2][s];
      #pragma unroll
      for (int e = 0; e < 8; ++e) f[e] = (__bf16)((float)f[e] * rn);
      af[g2][s] = f;
    }
  }

  float rs[2][16];
  #pragma unroll
  for (int g2 = 0; g2 < 2; ++g2)
    #pragma unroll
    for (int j = 0; j < 16; ++j) rs[g2][j] = 0.f;

  __syncthreads();  // buf0 staged (barrier drains vmcnt) + bsum init visible

  for (int c = 0; c < 8; ++c) {
    if (c < 7) stage(c + 1, (c + 1) & 1);   // issue next chunk FIRST
    const char* base = smem + (c & 1) * 65536;
    #pragma unroll
    for (int cf = 0; cf < 4; ++cf) {
      const int col_l = cf * 32 + lm;           // local col in chunk
      const int sw = (col_l & 31) << 4;
      f32x16 acc0 = {0.f};
      f32x16 acc1 = {0.f};
      #pragma unroll
      for (int s = 0; s < 16; ++s) {
        const uint4 raw = *(const uint4*)(base + col_l * 512 + ((s * 32 + lh * 16) ^ sw));
        const bf16x8 bfr = __builtin_bit_cast(bf16x8, raw);
        acc0 = __builtin_amdgcn_mfma_f32_32x32x16_bf16(af[0][s], bfr, acc0, 0, 0, 0);
        acc1 = __builtin_amdgcn_mfma_f32_32x32x16_bf16(af[1][s], bfr, acc1, 0, 0, 0);
      }
      #pragma unroll
      for (int j = 0; j < 16; ++j) {
        rs[0][j] += __builtin_amdgcn_exp2f(acc0[j] * K2EXP);
        rs[1][j] += __builtin_amdgcn_exp2f(acc1[j] * K2EXP);
      }
      if (pcf == c * 4 + cf && lm == (p & 31)) {
        #pragma unroll
        for (int j = 0; j < 16; ++j) {
          const int r0 = (j & 3) + 8 * (j >> 2) + 4 * lh;
          posl[w * 64 + r0]      = acc0[j] * K2EXP;   // log2-scaled logits
          posl[w * 64 + 32 + r0] = acc1[j] * K2EXP;
        }
      }
    }
    __syncthreads();  // chunk c fully read; chunk c+1 staged
  }

  // reduce row sums over the 32 column-lanes of each half-wave
  #pragma unroll
  for (int g2 = 0; g2 < 2; ++g2)
    #pragma unroll
    for (int j = 0; j < 16; ++j) {
      float v = rs[g2][j];
      #pragma unroll
      for (int m = 1; m <= 16; m <<= 1) v += __shfl_xor(v, m, 64);
      rs[g2][j] = v;
    }

  if (lm == 0) {  // lanes 0 and 32: 32 rows each
    float local = 0.f;
    #pragma unroll
    for (int g2 = 0; g2 < 2; ++g2)
      #pragma unroll
      for (int j = 0; j < 16; ++j) {
        const int r0 = g2 * 32 + (j & 3) + 8 * (j >> 2) + 4 * lh;
        const float cs = posl[w * 64 + r0];               // z/ln2
        const float S  = rs[g2][j] - __builtin_amdgcn_exp2f(cs);
        local += (__builtin_amdgcn_logf(S) - cs) * LN2F;  // ln(S) - z
      }
    atomicAdd(bsum, local);
  }
  __syncthreads();
  if (tid == 0) atomicAdd(out, *bsum * (1.0f / 131072.0f));
}

extern "C" void kernel_launch(void* const* d_in, const int* in_sizes, int n_in,
                              void* d_out, int out_size, void* d_ws, size_t ws_size,
                              hipStream_t stream) {
  (void)in_sizes; (void)n_in; (void)out_size; (void)ws_size;
  const float* l2 = (const float*)d_in[0];   // [131072, 256] fp32
  const float* g  = (const float*)d_in[1];   // [1024, 256] fp32
  float* out = (float*)d_out;

  char* ghat = (char*)d_ws;                  // 512 KB bf16, swizzled

  hipMemsetAsync(d_out, 0, sizeof(float), stream);
  k_ghat<<<256, 256, 0, stream>>>(g, ghat);
  k_main<<<256, 512, 0, stream>>>(l2, ghat, out);
}

// Round 3
// 166.998 us; speedup vs baseline: 1.2843x; 1.2843x over previous
//
#include <hip/hip_runtime.h>
#include <hip/hip_bf16.h>
#include <stdint.h>

typedef __bf16 bf16x8 __attribute__((ext_vector_type(8)));
typedef float  f32x16 __attribute__((ext_vector_type(16)));

#define K2EXP 7.2134752044448170f   /* log2(e)/T */
#define LN2F  0.6931471805599453f

__device__ __forceinline__ unsigned short f2bf(float f) {
  __bf16 h = (__bf16)f;
  return __builtin_bit_cast(unsigned short, h);
}

// ghat: row-normalized g_enc as bf16, pre-swizzled: byte kb of row r lands at
// r*512 + (kb ^ ((r&31)<<4))  -- full 32-slot XOR permutation per 512B row.
__global__ __launch_bounds__(256) void k_ghat(const float* __restrict__ g,
                                              char* __restrict__ ghat) {
  const int w = threadIdx.x >> 6, l = threadIdx.x & 63;
  const int row = blockIdx.x * 4 + w;
  const float4 v = *(const float4*)(g + (size_t)row * 256 + l * 4);
  float s = v.x * v.x + v.y * v.y + v.z * v.z + v.w * v.w;
  #pragma unroll
  for (int m = 1; m <= 32; m <<= 1) s += __shfl_xor(s, m, 64);
  const float rn = rsqrtf(s);
  ushort4 o;
  o.x = f2bf(v.x * rn); o.y = f2bf(v.y * rn);
  o.z = f2bf(v.z * rn); o.w = f2bf(v.w * rn);
  const int off = row * 512 + ((l * 8) ^ ((row & 31) << 4));
  *(ushort4*)(ghat + off) = o;
}

// Main fused kernel, sized to the compiler's 128-VGPR budget:
// 8 waves/block, 32 rows/wave (af[16] = 64 VGPRs, k=256 resident),
// B double-buffered through LDS in 32KB chunks, 2 blocks/CU for overlap.
__global__ __launch_bounds__(512, 4) void k_main(const float* __restrict__ l2,
                                                 const char* __restrict__ ghat,
                                                 float* __restrict__ out) {
  __shared__ __align__(16) char smem[2 * 32768 + 1024 + 64];
  float* posl = (float*)(smem + 65536);          // 256 floats
  float* bsum = (float*)(smem + 65536 + 1024);

  const int tid = threadIdx.x;
  const int w   = tid >> 6;      // 0..7
  const int l   = tid & 63;
  const int lm  = l & 31;
  const int lh  = l >> 5;
  const int wrb = blockIdx.x * 256 + w * 32;  // wave's first row
  const int p   = wrb >> 7;                   // positive column (wave-uniform)
  const int pcf = p >> 5;                     // global 32-col fragment of p

  if (tid == 0) *bsum = 0.f;

  auto stage = [&](int c, int buf) {
    const char* gsrc = ghat + c * 32768 + w * 4096 + l * 16;
    char* ldst = smem + buf * 32768 + w * 4096;
    #pragma unroll
    for (int i = 0; i < 4; ++i) {
      __builtin_amdgcn_global_load_lds(
          (const __attribute__((address_space(1))) void*)(gsrc + i * 1024),
          (__attribute__((address_space(3))) void*)(ldst + i * 1024),
          16, 0, 0);
    }
  };

  stage(0, 0);  // fly under the A-load

  // A load + pack + sum-of-squares, single HBM pass.
  // af[s]: row wrb+lm, k = s*16 + lh*8 .. +8
  bf16x8 af[16];
  float ssq = 0.f;
  {
    const float* rp = l2 + (size_t)(wrb + lm) * 256 + lh * 8;
    #pragma unroll
    for (int s = 0; s < 16; ++s) {
      const float4 a = *(const float4*)(rp + s * 16);
      const float4 b = *(const float4*)(rp + s * 16 + 4);
      ssq += a.x*a.x + a.y*a.y + a.z*a.z + a.w*a.w
           + b.x*b.x + b.y*b.y + b.z*b.z + b.w*b.w;
      bf16x8 f;
      f[0] = (__bf16)a.x; f[1] = (__bf16)a.y; f[2] = (__bf16)a.z; f[3] = (__bf16)a.w;
      f[4] = (__bf16)b.x; f[5] = (__bf16)b.y; f[6] = (__bf16)b.z; f[7] = (__bf16)b.w;
      af[s] = f;
      // cap load-hoisting: keep in-flight float4s bounded so we stay <128 VGPR
      if ((s & 3) == 3) __builtin_amdgcn_sched_barrier(0);
    }
  }
  // fold 1/||row|| into af in-register
  {
    const float rn = rsqrtf(ssq + __shfl_xor(ssq, 32, 64));
    #pragma unroll
    for (int s = 0; s < 16; ++s) {
      bf16x8 f = af[s];
      #pragma unroll
      for (int e = 0; e < 8; ++e) f[e] = (__bf16)((float)f[e] * rn);
      af[s] = f;
    }
  }

  float rs[16];
  #pragma unroll
  for (int j = 0; j < 16; ++j) rs[j] = 0.f;

  __syncthreads();  // buf0 staged (barrier drains vmcnt) + bsum init visible

  for (int c = 0; c < 16; ++c) {
    if (c < 15) stage(c + 1, (c + 1) & 1);   // issue next chunk FIRST
    const char* base = smem + (c & 1) * 32768;
    #pragma unroll
    for (int cf = 0; cf < 2; ++cf) {
      const int col_l = cf * 32 + lm;           // local col in 64-col chunk
      const int sw = (col_l & 31) << 4;
      f32x16 acc = {0.f};
      #pragma unroll
      for (int s = 0; s < 16; ++s) {
        const uint4 raw = *(const uint4*)(base + col_l * 512 + ((s * 32 + lh * 16) ^ sw));
        acc = __builtin_amdgcn_mfma_f32_32x32x16_bf16(
                  af[s], __builtin_bit_cast(bf16x8, raw), acc, 0, 0, 0);
      }
      #pragma unroll
      for (int j = 0; j < 16; ++j)
        rs[j] += __builtin_amdgcn_exp2f(acc[j] * K2EXP);
      if (pcf == c * 2 + cf && lm == (p & 31)) {
        #pragma unroll
        for (int j = 0; j < 16; ++j) {
          const int r0 = (j & 3) + 8 * (j >> 2) + 4 * lh;
          posl[w * 32 + r0] = acc[j] * K2EXP;   // log2-scaled positive logit
        }
      }
    }
    __syncthreads();  // chunk c fully read; chunk c+1 staged
  }

  // reduce row sums over the 32 column-lanes of each half-wave
  #pragma unroll
  for (int j = 0; j < 16; ++j) {
    float v = rs[j];
    #pragma unroll
    for (int m = 1; m <= 16; m <<= 1) v += __shfl_xor(v, m, 64);
    rs[j] = v;
  }

  if (lm == 0) {  // lanes 0 and 32: 16 rows each
    float local = 0.f;
    #pragma unroll
    for (int j = 0; j < 16; ++j) {
      const int r0 = (j & 3) + 8 * (j >> 2) + 4 * lh;
      const float cs = posl[w * 32 + r0];               // z/ln2
      const float S  = rs[j] - __builtin_amdgcn_exp2f(cs);
      local += (__builtin_amdgcn_logf(S) - cs) * LN2F;  // ln(S) - z
    }
    atomicAdd(bsum, local);
  }
  __syncthreads();
  if (tid == 0) atomicAdd(out, *bsum * (1.0f / 131072.0f));
}

extern "C" void kernel_launch(void* const* d_in, const int* in_sizes, int n_in,
                              void* d_out, int out_size, void* d_ws, size_t ws_size,
                              hipStream_t stream) {
  (void)in_sizes; (void)n_in; (void)out_size; (void)ws_size;
  const float* l2 = (const float*)d_in[0];   // [131072, 256] fp32
  const float* g  = (const float*)d_in[1];   // [1024, 256] fp32
  float* out = (float*)d_out;

  char* ghat = (char*)d_ws;                  // 512 KB bf16, swizzled

  hipMemsetAsync(d_out, 0, sizeof(float), stream);
  k_ghat<<<256, 256, 0, stream>>>(g, ghat);
  k_main<<<512, 512, 0, stream>>>(l2, ghat, out);
}